// Round 12
// baseline (949.206 us; speedup 1.0000x reference)
//
#include <hip/hip_runtime.h>
#include <math.h>

#define Bk   32
#define Nk   256
#define Fk   8
#define Hk   8
#define Dk   8
#define HIDk 512
#define HDk  64
#define NROWk 776
#define CAPk 96
#define GSLICE 4

typedef __attribute__((ext_vector_type(8))) short short8;
typedef __attribute__((ext_vector_type(4))) float f32x4;

__device__ __forceinline__ float lrelu(float x){ return fmaxf(x, 0.2f*x); }

__device__ __forceinline__ unsigned short f2bf(float x){
  unsigned int u = __float_as_uint(x);
  unsigned int r = (u + 0x7fffu + ((u>>16)&1u)) >> 16;
  return (unsigned short)r;
}

// support[b,n,c] = b_self1[c] + sum_f x[b,n,f]*w_self1[f,c];  x[b,n,f]=inp[b,768+f,n]
__global__ void k_support(const float* __restrict__ inp, const float* __restrict__ w1,
                          const float* __restrict__ b1, float* __restrict__ support){
  int bn = blockIdx.x; int b = bn >> 8; int n = bn & 255;
  const float* xin = inp + (size_t)b*NROWk*Nk + (size_t)(3*Nk)*Nk + n;
  float x[8];
#pragma unroll
  for (int f=0; f<8; f++) x[f] = xin[(size_t)f*Nk];
  int t = threadIdx.x;
  for (int c = t; c < HIDk; c += 256){
    float s = b1[c];
#pragma unroll
    for (int f=0; f<8; f++) s += x[f]*w1[f*HIDk + c];
    support[(size_t)bn*HIDk + c] = s;
  }
}

// sup[b,h,n,d] = sum_c support[b,n,c]*W[c, h*8+d]
__global__ void k_sup(const float* __restrict__ support, const float* __restrict__ W,
                      float* __restrict__ sup){
  __shared__ float srow[4][HIDk+1];
  int b = blockIdx.x >> 6; int n0 = (blockIdx.x & 63) << 2;
  int t = threadIdx.x;
  for (int i = t; i < 4*HIDk; i += 256)
    srow[i>>9][i&511] = support[((size_t)b*Nk + n0 + (i>>9))*HIDk + (i&511)];
  __syncthreads();
  int nl = t >> 6, hd = t & 63;
  const float* srw = srow[nl];
  float s = 0.f;
  for (int c=0;c<HIDk;c++) s += srw[c]*W[c*HDk + hd];
  int h = hd >> 3, d = hd & 7;
  sup[(((size_t)b*Hk + h)*Nk + (n0+nl))*Dk + d] = s;
}

// fu[b,h,n] = sup . Wu[h,:],  fv likewise
__global__ void k_fuv(const float* __restrict__ sup, const float* __restrict__ Wu,
                      const float* __restrict__ Wv, float* __restrict__ fu, float* __restrict__ fv){
  int i = blockIdx.x*256 + threadIdx.x;     // (b*H+h)*N + n
  int h = (i >> 8) & 7;
  const float* s = sup + (size_t)i*Dk;
  float a=0.f, v=0.f;
#pragma unroll
  for (int d=0; d<8; d++){ float sv = s[d]; a += sv*Wu[h*8+d]; v += sv*Wv[h*8+d]; }
  fu[i] = a; fv[i] = v;
}

__global__ void k_rowzero(const float* __restrict__ inp, int rowOff,
                          int* __restrict__ z_cnt, int* __restrict__ z_idx){
  int b = blockIdx.x >> 8, j = blockIdx.x & 255;
  float v = inp[(size_t)b*NROWk*Nk + (size_t)(rowOff+j)*Nk + threadIdx.x];
  __shared__ int flag;
  if (threadIdx.x==0) flag = 0;
  __syncthreads();
  if (v != 0.0f) atomicOr(&flag, 1);
  __syncthreads();
  if (threadIdx.x==0 && flag==0){ int idx = atomicAdd(&z_cnt[b], 1); z_idx[b*Nk + idx] = j; }
}

__global__ void k_csc(const float* __restrict__ inp, int rowOff,
                      int* __restrict__ col_cnt, int* __restrict__ row_idx){
  int b = blockIdx.x >> 8, k = blockIdx.x & 255;
  int j = threadIdx.x;
  __shared__ unsigned char nzf[Nk];
  nzf[j] = (inp[(size_t)b*NROWk*Nk + (size_t)(rowOff+j)*Nk + k] != 0.0f) ? 1 : 0;
  __syncthreads();
  if (j == 0){
    int c = 0; int base = (b*Nk + k)*CAPk;
    for (int jj=0; jj<Nk; jj++) if (nzf[jj]){ if (c < CAPk) row_idx[base + c] = jj; c++; }
    col_cnt[b*Nk + k] = (c > CAPk) ? CAPk : c;
  }
}

__global__ void k_zsum(const float* __restrict__ fu, const float* __restrict__ fv,
                       const int* __restrict__ z_cnt, const int* __restrict__ z_idx,
                       float* __restrict__ zsum){
  int i = blockIdx.x*256 + threadIdx.x;
  int bh = i >> 8; int b = bh >> 3;
  int zc = z_cnt[b];
  float fvi = fv[i], s = 0.f;
  for (int t=0; t<zc; t++){ float x = fvi + fu[(bh<<8) + z_idx[b*Nk+t]]; s += lrelu(x); }
  zsum[i] = s;
}

// per (b,h, 32-row tile): mw -> masked softmax -> attn @ sup
__global__ __launch_bounds__(256) void k_attn(const float* __restrict__ sup,
    const float* __restrict__ fu_g, const float* __restrict__ fv_g,
    const float* __restrict__ zsum_g, const int* __restrict__ z_cnt,
    const int* __restrict__ col_cnt, const int* __restrict__ row_idx,
    float* __restrict__ ao){
  __shared__ float fu_s[Nk];
  __shared__ float fvt[32];
  __shared__ float zs[32];
  __shared__ float sup_s[Nk*Dk];
  __shared__ float mw[32][Nk+1];
  __shared__ unsigned char maskk[Nk];
  int blk = blockIdx.x;
  int bh = blk >> 3;
  int b  = bh >> 3;
  int h  = bh & 7;
  int i0 = (blk & 7) << 5;
  int t = threadIdx.x;
  fu_s[t] = fu_g[(bh<<8) + t];
  if (t < 32){ fvt[t] = fv_g[(bh<<8) + i0 + t]; zs[t] = zsum_g[(bh<<8) + i0 + t]; }
  for (int i = t; i < Nk*Dk; i += 256) sup_s[i] = sup[(size_t)bh*Nk*Dk + i];
  int zc = z_cnt[b];
  int cnt = col_cnt[b*Nk + t];
  maskk[t] = (cnt > 0 || zc > 0) ? 1 : 0;
  __syncthreads();
  {
    float acc[32];
#pragma unroll
    for (int i=0;i<32;i++) acc[i]=0.f;
    const int* ridx = row_idx + (size_t)(b*Nk + t)*CAPk;
    for (int s=0;s<cnt;s++){
      float fuj = fu_s[ridx[s]];
#pragma unroll
      for (int i=0;i<32;i++){ float x = fvt[i] + fuj; acc[i] += fmaxf(x, 0.2f*x); }
    }
#pragma unroll
    for (int i=0;i<32;i++) mw[i][t] = acc[i] + 1e-6f*zs[i];
  }
  __syncthreads();
  int wv = t>>6, lane = t&63;
  for (int i = wv; i < 32; i += 4){
    float vals[4]; float m = -1e30f;
#pragma unroll
    for (int q=0;q<4;q++){ int kk = lane + (q<<6); float v = mw[i][kk]; vals[q]=v; if (maskk[kk]) m = fmaxf(m, v); }
#pragma unroll
    for (int s=32;s>0;s>>=1) m = fmaxf(m, __shfl_xor(m, s));
    float e[4]; float sum=0.f;
#pragma unroll
    for (int q=0;q<4;q++){ int kk = lane + (q<<6); float p = maskk[kk] ? expf(vals[q]-m) : 0.f; e[q]=p; sum+=p; }
#pragma unroll
    for (int s=32;s>0;s>>=1) sum += __shfl_xor(sum, s);
    float inv = (sum > 0.f) ? 1.f/sum : 0.f;
#pragma unroll
    for (int q=0;q<4;q++){ int kk = lane + (q<<6); mw[i][kk] = e[q]*inv; }
  }
  __syncthreads();
  int il = t>>3, d = t&7;
  float s = 0.f;
  for (int kk=0; kk<Nk; kk++) s += mw[il][kk]*sup_s[kk*Dk + d];
  ao[((size_t)b*Nk + i0 + il)*HDk + (h<<3) + d] = s;
}

// gat = tanh(ao + b_gat + support@projW + projB)   (in-place over ao)
__global__ void k_gatout(const float* __restrict__ ao, const float* __restrict__ support,
                         const float* __restrict__ pW, const float* __restrict__ pB,
                         const float* __restrict__ bg, float* __restrict__ gat){
  __shared__ float srow[4][HIDk+1];
  int b = blockIdx.x >> 6; int n0 = (blockIdx.x & 63) << 2;
  int t = threadIdx.x;
  for (int i = t; i < 4*HIDk; i += 256)
    srow[i>>9][i&511] = support[((size_t)b*Nk + n0 + (i>>9))*HIDk + (i&511)];
  __syncthreads();
  int nl = t >> 6, hd = t & 63;
  const float* srw = srow[nl];
  float s = pB[hd] + bg[hd];
  for (int c=0;c<HIDk;c++) s += srw[c]*pW[c*HDk + hd];
  size_t idx = ((size_t)b*Nk + n0 + nl)*HDk + hd;
  gat[idx] = tanhf(s + ao[idx]);
}

// 64x64 tile transpose + bf16 convert: dst[n][k] = (bf16)src[k][n]  (512x512)
__global__ void k_prepT(const float* __restrict__ w_self2, const float* __restrict__ sem_w1,
                        unsigned short* __restrict__ w2T, unsigned short* __restrict__ w1T){
  __shared__ float tile[64][65];
  const float* src = blockIdx.y ? sem_w1 : w_self2;
  unsigned short* dst = blockIdx.y ? w1T : w2T;
  int tk = (blockIdx.x >> 3) << 6;
  int tn = (blockIdx.x & 7) << 6;
  int t = threadIdx.x;
  for (int i = t; i < 64*64; i += 256){
    int r = i >> 6, c = i & 63;
    tile[r][c] = src[(size_t)(tk + r)*HIDk + tn + c];
  }
  __syncthreads();
  for (int i = t; i < 64*64; i += 256){
    int r = i >> 6, c = i & 63;
    dst[(size_t)(tn + r)*HIDk + tk + c] = f2bf(tile[c][r]);
  }
}

// MFMA GEMM: out = A[M][512] @ BT^T, BT = bf16 [512 n][512 k]. NF=8, col-split grid.y=4.
// MODE 0 (S2): out_f[remap(m)*512+col] = acc + bias[col]   (emb channel 0 layout)
// MODE 1 (WSEM): atomicAdd(wsem[m], sum_colslice tanh(acc+bias)*w2)  (wsem pre-zeroed)
template<int MODE>
__global__ __launch_bounds__(256) void k_gemm512(
    const float* __restrict__ A, const unsigned short* __restrict__ BT,
    const float* __restrict__ bias, const float* __restrict__ w2,
    float* __restrict__ outf){
  constexpr int NF = 8;
  constexpr int NPB = NF*16;     // 128
  __shared__ uint4 As4[64*4];
  __shared__ uint4 Bs4[NPB*4];
  int row0 = blockIdx.x << 6;
  int col0 = blockIdx.y * NPB;
  int t = threadIdx.x;
  int w = t >> 6, l = t & 63;
  f32x4 acc[NF];
#pragma unroll
  for (int i=0;i<NF;i++) acc[i] = (f32x4){0.f,0.f,0.f,0.f};

  int lrA = t >> 2;          // 0..63 (row for staging)
  int slot = t & 3;          // k chunk-of-8 for staging
  const float* aptr = A + (size_t)(row0 + lrA)*HIDk + slot*8;
  const unsigned short* bbase = BT + (size_t)(col0 + lrA)*HIDk + slot*8;

  // preload kc = 0
  float4 av0 = *(const float4*)(aptr);
  float4 av1 = *(const float4*)(aptr + 4);
  uint4 bv0  = *(const uint4*)(bbase);
  uint4 bv1  = *(const uint4*)(bbase + (size_t)64*HIDk);

  for (int kc = 0; kc < 512; kc += 32){
    uint4 apk;
    unsigned short* ap = (unsigned short*)&apk;
    ap[0]=f2bf(av0.x); ap[1]=f2bf(av0.y); ap[2]=f2bf(av0.z); ap[3]=f2bf(av0.w);
    ap[4]=f2bf(av1.x); ap[5]=f2bf(av1.y); ap[6]=f2bf(av1.z); ap[7]=f2bf(av1.w);
    __syncthreads();
    As4[(lrA<<2) + (slot ^ ((lrA>>1)&3))] = apk;
    Bs4[(lrA<<2) + (slot ^ ((lrA>>1)&3))] = bv0;
    {
      int ln = 64 + lrA;
      Bs4[(ln<<2) + (slot ^ ((ln>>1)&3))] = bv1;
    }
    __syncthreads();
    if (kc + 32 < 512){
      av0 = *(const float4*)(aptr + kc + 32);
      av1 = *(const float4*)(aptr + kc + 36);
      bv0 = *(const uint4*)(bbase + kc + 32);
      bv1 = *(const uint4*)(bbase + (size_t)64*HIDk + kc + 32);
    }
    int aRow = (w<<4) + (l&15);
    int ks = l>>4;
    short8 af = *(const short8*)&As4[(aRow<<2) + (ks ^ ((aRow>>1)&3))];
#pragma unroll
    for (int nf = 0; nf < NF; nf++){
      int bRow = (nf<<4) + (l&15);
      short8 bfr = *(const short8*)&Bs4[(bRow<<2) + (ks ^ ((bRow>>1)&3))];
      acc[nf] = __builtin_amdgcn_mfma_f32_16x16x32_bf16(af, bfr, acc[nf], 0, 0, 0);
    }
  }
  int colB = l & 15, rg = l >> 4;
  if (MODE == 0){
#pragma unroll
    for (int nf = 0; nf < NF; nf++){
      int col = col0 + (nf<<4) + colB;
      float bb = bias[col];
#pragma unroll
      for (int r = 0; r < 4; r++){
        int m = row0 + (w<<4) + (rg<<2) + r;
        int mo = ((m>>8)<<10) + (m&255);   // emb channel-0 row remap
        outf[(size_t)mo*HIDk + col] = acc[nf][r] + bb;
      }
    }
  } else {
    float s0=0.f, s1=0.f, s2v=0.f, s3=0.f;
#pragma unroll
    for (int nf = 0; nf < NF; nf++){
      int col = col0 + (nf<<4) + colB;
      float bb = bias[col], wv = w2[col];
      s0  += tanhf(acc[nf][0]+bb)*wv;
      s1  += tanhf(acc[nf][1]+bb)*wv;
      s2v += tanhf(acc[nf][2]+bb)*wv;
      s3  += tanhf(acc[nf][3]+bb)*wv;
    }
#pragma unroll
    for (int mk = 1; mk < 16; mk <<= 1){
      s0  += __shfl_xor(s0, mk);  s1 += __shfl_xor(s1, mk);
      s2v += __shfl_xor(s2v, mk); s3 += __shfl_xor(s3, mk);
    }
    if (colB == 0){
      int m = row0 + (w<<4) + (rg<<2);
      atomicAdd(&outf[m+0], s0);
      atomicAdd(&outf[m+1], s1);
      atomicAdd(&outf[m+2], s2v);
      atomicAdd(&outf[m+3], s3);
    }
  }
}

// emb[b,chan,n,:] = gat @ W + bias  (K=64, 8 rows / block)
__global__ void k_mlp(const float* __restrict__ gat, const float* __restrict__ W,
                      const float* __restrict__ bias, float* __restrict__ emb, int chan){
  __shared__ float g[8][HDk];
  int b = blockIdx.x >> 5; int n0 = (blockIdx.x & 31) << 3;
  int t = threadIdx.x;
  for (int i=t;i<8*HDk;i+=256) g[i>>6][i&63] = gat[((size_t)b*Nk + n0 + (i>>6))*HDk + (i&63)];
  __syncthreads();
  for (int pass=0;pass<2;pass++){
    int o = t + (pass<<8);
    float acc[8]={0,0,0,0,0,0,0,0};
    for (int c=0;c<HDk;c++){
      float wv = W[c*HIDk+o];
#pragma unroll
      for (int r=0;r<8;r++) acc[r] += g[r][c]*wv;
    }
    float bs = bias[o];
#pragma unroll
    for (int r=0;r<8;r++) emb[(((size_t)b*4 + chan)*Nk + n0+r)*HIDk + o] = acc[r]+bs;
  }
}

// beta = softmax_c(wsem); fused[b,n,:] = sum_c beta_c * emb[b,c,n,:]
__global__ void k_fused(const float* __restrict__ emb, const float* __restrict__ wsem,
                        float* __restrict__ fused){
  int bn = blockIdx.x; int b = bn>>8, n = bn&255;
  float w0 = wsem[((b<<2)+0)*Nk+n], w1 = wsem[((b<<2)+1)*Nk+n];
  float w2 = wsem[((b<<2)+2)*Nk+n], w3 = wsem[((b<<2)+3)*Nk+n];
  float m = fmaxf(fmaxf(w0,w1),fmaxf(w2,w3));
  float e0=expf(w0-m),e1=expf(w1-m),e2=expf(w2-m),e3=expf(w3-m);
  float inv = 1.f/(e0+e1+e2+e3);
  e0*=inv; e1*=inv; e2*=inv; e3*=inv;
  const float* e = emb + (((size_t)(b<<2))*Nk + n)*HIDk;
  size_t cs = (size_t)Nk*HIDk;
  for (int o = threadIdx.x; o < HIDk; o += 128)
    fused[(size_t)bn*HIDk + o] = e0*e[o] + e1*e[o+cs] + e2*e[o+2*cs] + e3*e[o+3*cs];
}

__global__ void k_cmean(const float* __restrict__ fused, float* __restrict__ cmean){
  int b = blockIdx.x >> 1; int o = ((blockIdx.x & 1) << 8) + threadIdx.x;
  float s=0.f;
  for (int n=0;n<Nk;n++) s += fused[((size_t)b*Nk+n)*HIDk + o];
  cmean[b*HIDk+o] = s*(1.f/Nk);
}

__global__ void k_norm(const float* __restrict__ fused, const float* __restrict__ cmean,
                       float* __restrict__ xc){
  __shared__ float red[4];
  int bn = blockIdx.x; int b = bn>>8;
  int t = threadIdx.x;
  float v0 = fused[(size_t)bn*HIDk + t]       - cmean[b*HIDk + t];
  float v1 = fused[(size_t)bn*HIDk + t+256]   - cmean[b*HIDk + t+256];
  float ss = v0*v0 + v1*v1;
#pragma unroll
  for (int s=32;s>0;s>>=1) ss += __shfl_xor(ss, s);
  if ((t&63)==0) red[t>>6] = ss;
  __syncthreads();
  float tot = red[0]+red[1]+red[2]+red[3];
  float inv = 1.0f/sqrtf(1e-6f + tot);
  xc[(size_t)bn*HIDk + t]     = v0*inv;
  xc[(size_t)bn*HIDk + t+256] = v1*inv;
}

// per (n,q): part[b][(n*4+q)][g] = sum_{c in q-slice} xc[b,n,c]*gen_w[n*512+c, g]
// xc reads are wave-uniform (scalar-load path); 4 independent gen_w loads in flight.
__global__ __launch_bounds__(256) void k_gen(const float* __restrict__ xc, const float* __restrict__ genw,
                                             float* __restrict__ part){
  int n = blockIdx.x, q = blockIdx.y;
  int t = threadIdx.x;
  int c0 = q << 7;    // q*128
  float acc[32];
#pragma unroll
  for (int b=0;b<32;b++) acc[b]=0.f;
  const float* wp = genw + ((size_t)n*HIDk + c0)*Nk + t;
  for (int c = 0; c < 128; c += 4){
    float w0 = wp[(size_t)(c+0)*Nk];
    float w1 = wp[(size_t)(c+1)*Nk];
    float w2 = wp[(size_t)(c+2)*Nk];
    float w3 = wp[(size_t)(c+3)*Nk];
#pragma unroll
    for (int b = 0; b < 32; b++){
      const float4 xv = *(const float4*)(xc + ((size_t)b*Nk + n)*HIDk + c0 + c);
      acc[b] = fmaf(xv.x, w0, fmaf(xv.y, w1, fmaf(xv.z, w2, fmaf(xv.w, w3, acc[b]))));
    }
  }
#pragma unroll
  for (int b=0;b<32;b++) part[((size_t)b*(Nk*GSLICE) + (n<<2) + q)*Nk + t] = acc[b];
}

__global__ void k_final(const float* __restrict__ part, const float* __restrict__ genb,
                        float* __restrict__ out){
  int b = blockIdx.x, g = threadIdx.x;
  float s0=0.f, s1=0.f, s2=0.f, s3=0.f;
  const float* p = part + (size_t)b*(Nk*GSLICE)*Nk + g;
  for (int s = 0; s < Nk*GSLICE; s += 4){
    s0 += p[(size_t)(s+0)*Nk];
    s1 += p[(size_t)(s+1)*Nk];
    s2 += p[(size_t)(s+2)*Nk];
    s3 += p[(size_t)(s+3)*Nk];
  }
  float s = genb[g] + s0+s1+s2+s3;
  out[b*Nk + g] = 1.f/(1.f + expf(-s));
}

extern "C" void kernel_launch(void* const* d_in, const int* in_sizes, int n_in,
                              void* d_out, int out_size, void* d_ws, size_t ws_size,
                              hipStream_t stream){
  const float* inp    = (const float*)d_in[0];
  const float* W_gat  = (const float*)d_in[1];
  const float* Wu     = (const float*)d_in[2];
  const float* Wv     = (const float*)d_in[3];
  const float* b_gat  = (const float*)d_in[4];
  const float* projW  = (const float*)d_in[5];
  const float* projB  = (const float*)d_in[6];
  const float* w_self1= (const float*)d_in[7];
  const float* b_self1= (const float*)d_in[8];
  const float* w_mlp  = (const float*)d_in[9];
  const float* b_mlp  = (const float*)d_in[10];
  const float* w_self2= (const float*)d_in[11];
  const float* b_self2= (const float*)d_in[12];
  const float* sem_w1 = (const float*)d_in[13];
  const float* sem_b1 = (const float*)d_in[14];
  const float* sem_w2 = (const float*)d_in[15];
  const float* gen_w  = (const float*)d_in[16];
  const float* gen_b  = (const float*)d_in[17];
  float* out = (float*)d_out;
  (void)in_sizes; (void)n_in; (void)out_size; (void)ws_size;

  float* w = (float*)d_ws;
  size_t off = 0;
  auto A = [&](size_t n){ float* p = w + off; off += (n + 63) & ~(size_t)63; return p; };
  float* support = A((size_t)Bk*Nk*HIDk);
  float* emb     = A((size_t)Bk*4*Nk*HIDk);
  float* sup0 = A((size_t)Bk*Hk*Nk*Dk); float* sup1 = A((size_t)Bk*Hk*Nk*Dk);
  float* fu0  = A(Bk*Hk*Nk); float* fu1 = A(Bk*Hk*Nk);
  float* fv0  = A(Bk*Hk*Nk); float* fv1 = A(Bk*Hk*Nk);
  float* zs0  = A(Bk*Hk*Nk); float* zs1 = A(Bk*Hk*Nk);
  float* ao0  = A((size_t)Bk*Nk*HDk); float* ao1 = A((size_t)Bk*Nk*HDk);
  float* wsem = A(Bk*4*Nk);
  float* fused= A((size_t)Bk*Nk*HIDk);
  float* cmean= A(Bk*HIDk);
  float* part = A((size_t)Bk*Nk*GSLICE*Nk);
  float* tbuf = A(2*HIDk*HIDk/2);       // 2 bf16 matrices of 512x512 = 1MB
  unsigned short* w2T = (unsigned short*)tbuf;
  unsigned short* w1T = w2T + HIDk*HIDk;
  int* ib  = (int*)(w + off);
  int* zc0 = ib;              int* zc1 = zc0 + Bk;
  int* zi0 = zc1 + Bk;        int* zi1 = zi0 + Bk*Nk;
  int* cc0 = zi1 + Bk*Nk;     int* cc1 = cc0 + Bk*Nk;
  int* ri0 = cc1 + Bk*Nk;     int* ri1 = ri0 + (size_t)Bk*Nk*CAPk;

  hipMemsetAsync(zc0, 0, 2*Bk*sizeof(int), stream);
  hipMemsetAsync(wsem, 0, (size_t)Bk*4*Nk*sizeof(float), stream);
  k_prepT<<<dim3(64,2), 256, 0, stream>>>(w_self2, sem_w1, w2T, w1T);
  k_support<<<Bk*Nk, 256, 0, stream>>>(inp, w_self1, b_self1, support);
  k_sup<<<Bk*(Nk/4), 256, 0, stream>>>(support, W_gat, sup0);
  k_sup<<<Bk*(Nk/4), 256, 0, stream>>>(support, W_gat + 2*HIDk*HDk, sup1);
  k_fuv<<<Bk*Hk*Nk/256, 256, 0, stream>>>(sup0, Wu, Wv, fu0, fv0);
  k_fuv<<<Bk*Hk*Nk/256, 256, 0, stream>>>(sup1, Wu + 2*Hk*Dk, Wv + 2*Hk*Dk, fu1, fv1);
  k_rowzero<<<Bk*Nk, 256, 0, stream>>>(inp, 0,    zc0, zi0);
  k_rowzero<<<Bk*Nk, 256, 0, stream>>>(inp, 2*Nk, zc1, zi1);
  k_csc<<<Bk*Nk, 256, 0, stream>>>(inp, 0,    cc0, ri0);
  k_csc<<<Bk*Nk, 256, 0, stream>>>(inp, 2*Nk, cc1, ri1);
  k_zsum<<<Bk*Hk*Nk/256, 256, 0, stream>>>(fu0, fv0, zc0, zi0, zs0);
  k_zsum<<<Bk*Hk*Nk/256, 256, 0, stream>>>(fu1, fv1, zc1, zi1, zs1);
  k_attn<<<Bk*Hk*(Nk/32), 256, 0, stream>>>(sup0, fu0, fv0, zs0, zc0, cc0, ri0, ao0);
  k_attn<<<Bk*Hk*(Nk/32), 256, 0, stream>>>(sup1, fu1, fv1, zs1, zc1, cc1, ri1, ao1);
  k_gatout<<<Bk*(Nk/4), 256, 0, stream>>>(ao0, support, projW,                projB,         b_gat,         ao0);
  k_gatout<<<Bk*(Nk/4), 256, 0, stream>>>(ao1, support, projW + 2*HIDk*HDk,   projB + 2*HDk, b_gat + 2*HDk, ao1);
  k_gemm512<0><<<dim3(128,4), 256, 0, stream>>>(support, w2T, b_self2, nullptr, emb);
  k_mlp<<<Bk*(Nk/8), 256, 0, stream>>>(ao0, w_mlp,               b_mlp,          emb, 1);
  k_mlp<<<Bk*(Nk/8), 256, 0, stream>>>(ao1, w_mlp + HDk*HIDk,    b_mlp + HIDk,   emb, 2);
  k_mlp<<<Bk*(Nk/8), 256, 0, stream>>>(ao1, w_mlp + 2*HDk*HIDk,  b_mlp + 2*HIDk, emb, 3);
  k_gemm512<1><<<dim3(512,4), 256, 0, stream>>>(emb, w1T, sem_b1, sem_w2, wsem);
  k_fused<<<Bk*Nk, 128, 0, stream>>>(emb, wsem, fused);
  k_cmean<<<Bk*2, 256, 0, stream>>>(fused, cmean);
  k_norm<<<Bk*Nk, 256, 0, stream>>>(fused, cmean, fused);
  k_gen<<<dim3(Nk, GSLICE), 256, 0, stream>>>(fused, gen_w, part);
  k_final<<<Bk, 256, 0, stream>>>(part, gen_b, out);
}

// Round 14
// 815.049 us; speedup vs baseline: 1.1646x; 1.1646x over previous
//
#include <hip/hip_runtime.h>
#include <math.h>

#define Bk   32
#define Nk   256
#define Fk   8
#define Hk   8
#define Dk   8
#define HIDk 512
#define HDk  64
#define NROWk 776
#define CAPk 96
#define GSLICE 4

typedef __attribute__((ext_vector_type(8))) short short8;
typedef __attribute__((ext_vector_type(4))) float f32x4;

__device__ __forceinline__ float lrelu(float x){ return fmaxf(x, 0.2f*x); }

__device__ __forceinline__ unsigned short f2bf(float x){
  unsigned int u = __float_as_uint(x);
  unsigned int r = (u + 0x7fffu + ((u>>16)&1u)) >> 16;
  return (unsigned short)r;
}

// support[b,n,c] = b_self1[c] + sum_f x[b,n,f]*w_self1[f,c];  x[b,n,f]=inp[b,768+f,n]
__global__ void k_support(const float* __restrict__ inp, const float* __restrict__ w1,
                          const float* __restrict__ b1, float* __restrict__ support){
  int bn = blockIdx.x; int b = bn >> 8; int n = bn & 255;
  const float* xin = inp + (size_t)b*NROWk*Nk + (size_t)(3*Nk)*Nk + n;
  float x[8];
#pragma unroll
  for (int f=0; f<8; f++) x[f] = xin[(size_t)f*Nk];
  int t = threadIdx.x;
  for (int c = t; c < HIDk; c += 256){
    float s = b1[c];
#pragma unroll
    for (int f=0; f<8; f++) s += x[f]*w1[f*HIDk + c];
    support[(size_t)bn*HIDk + c] = s;
  }
}

// sup[b,h,n,d] = sum_c support[b,n,c]*W[c, h*8+d]
__global__ void k_sup(const float* __restrict__ support, const float* __restrict__ W,
                      float* __restrict__ sup){
  __shared__ float srow[4][HIDk+1];
  int b = blockIdx.x >> 6; int n0 = (blockIdx.x & 63) << 2;
  int t = threadIdx.x;
  for (int i = t; i < 4*HIDk; i += 256)
    srow[i>>9][i&511] = support[((size_t)b*Nk + n0 + (i>>9))*HIDk + (i&511)];
  __syncthreads();
  int nl = t >> 6, hd = t & 63;
  const float* srw = srow[nl];
  float s = 0.f;
  for (int c=0;c<HIDk;c++) s += srw[c]*W[c*HDk + hd];
  int h = hd >> 3, d = hd & 7;
  sup[(((size_t)b*Hk + h)*Nk + (n0+nl))*Dk + d] = s;
}

// fu[b,h,n] = sup . Wu[h,:],  fv likewise
__global__ void k_fuv(const float* __restrict__ sup, const float* __restrict__ Wu,
                      const float* __restrict__ Wv, float* __restrict__ fu, float* __restrict__ fv){
  int i = blockIdx.x*256 + threadIdx.x;     // (b*H+h)*N + n
  int h = (i >> 8) & 7;
  const float* s = sup + (size_t)i*Dk;
  float a=0.f, v=0.f;
#pragma unroll
  for (int d=0; d<8; d++){ float sv = s[d]; a += sv*Wu[h*8+d]; v += sv*Wv[h*8+d]; }
  fu[i] = a; fv[i] = v;
}

__global__ void k_rowzero(const float* __restrict__ inp, int rowOff,
                          int* __restrict__ z_cnt, int* __restrict__ z_idx){
  int b = blockIdx.x >> 8, j = blockIdx.x & 255;
  float v = inp[(size_t)b*NROWk*Nk + (size_t)(rowOff+j)*Nk + threadIdx.x];
  __shared__ int flag;
  if (threadIdx.x==0) flag = 0;
  __syncthreads();
  if (v != 0.0f) atomicOr(&flag, 1);
  __syncthreads();
  if (threadIdx.x==0 && flag==0){ int idx = atomicAdd(&z_cnt[b], 1); z_idx[b*Nk + idx] = j; }
}

__global__ void k_csc(const float* __restrict__ inp, int rowOff,
                      int* __restrict__ col_cnt, int* __restrict__ row_idx){
  int b = blockIdx.x >> 8, k = blockIdx.x & 255;
  int j = threadIdx.x;
  __shared__ unsigned char nzf[Nk];
  nzf[j] = (inp[(size_t)b*NROWk*Nk + (size_t)(rowOff+j)*Nk + k] != 0.0f) ? 1 : 0;
  __syncthreads();
  if (j == 0){
    int c = 0; int base = (b*Nk + k)*CAPk;
    for (int jj=0; jj<Nk; jj++) if (nzf[jj]){ if (c < CAPk) row_idx[base + c] = jj; c++; }
    col_cnt[b*Nk + k] = (c > CAPk) ? CAPk : c;
  }
}

__global__ void k_zsum(const float* __restrict__ fu, const float* __restrict__ fv,
                       const int* __restrict__ z_cnt, const int* __restrict__ z_idx,
                       float* __restrict__ zsum){
  int i = blockIdx.x*256 + threadIdx.x;
  int bh = i >> 8; int b = bh >> 3;
  int zc = z_cnt[b];
  float fvi = fv[i], s = 0.f;
  for (int t=0; t<zc; t++){ float x = fvi + fu[(bh<<8) + z_idx[b*Nk+t]]; s += lrelu(x); }
  zsum[i] = s;
}

// per (b,h, 32-row tile): mw -> masked softmax -> attn @ sup
__global__ __launch_bounds__(256) void k_attn(const float* __restrict__ sup,
    const float* __restrict__ fu_g, const float* __restrict__ fv_g,
    const float* __restrict__ zsum_g, const int* __restrict__ z_cnt,
    const int* __restrict__ col_cnt, const int* __restrict__ row_idx,
    float* __restrict__ ao){
  __shared__ float fu_s[Nk];
  __shared__ float fvt[32];
  __shared__ float zs[32];
  __shared__ float sup_s[Nk*Dk];
  __shared__ float mw[32][Nk+1];
  __shared__ unsigned char maskk[Nk];
  int blk = blockIdx.x;
  int bh = blk >> 3;
  int b  = bh >> 3;
  int h  = bh & 7;
  int i0 = (blk & 7) << 5;
  int t = threadIdx.x;
  fu_s[t] = fu_g[(bh<<8) + t];
  if (t < 32){ fvt[t] = fv_g[(bh<<8) + i0 + t]; zs[t] = zsum_g[(bh<<8) + i0 + t]; }
  for (int i = t; i < Nk*Dk; i += 256) sup_s[i] = sup[(size_t)bh*Nk*Dk + i];
  int zc = z_cnt[b];
  int cnt = col_cnt[b*Nk + t];
  maskk[t] = (cnt > 0 || zc > 0) ? 1 : 0;
  __syncthreads();
  {
    float acc[32];
#pragma unroll
    for (int i=0;i<32;i++) acc[i]=0.f;
    const int* ridx = row_idx + (size_t)(b*Nk + t)*CAPk;
    for (int s=0;s<cnt;s++){
      float fuj = fu_s[ridx[s]];
#pragma unroll
      for (int i=0;i<32;i++){ float x = fvt[i] + fuj; acc[i] += fmaxf(x, 0.2f*x); }
    }
#pragma unroll
    for (int i=0;i<32;i++) mw[i][t] = acc[i] + 1e-6f*zs[i];
  }
  __syncthreads();
  int wv = t>>6, lane = t&63;
  for (int i = wv; i < 32; i += 4){
    float vals[4]; float m = -1e30f;
#pragma unroll
    for (int q=0;q<4;q++){ int kk = lane + (q<<6); float v = mw[i][kk]; vals[q]=v; if (maskk[kk]) m = fmaxf(m, v); }
#pragma unroll
    for (int s=32;s>0;s>>=1) m = fmaxf(m, __shfl_xor(m, s));
    float e[4]; float sum=0.f;
#pragma unroll
    for (int q=0;q<4;q++){ int kk = lane + (q<<6); float p = maskk[kk] ? expf(vals[q]-m) : 0.f; e[q]=p; sum+=p; }
#pragma unroll
    for (int s=32;s>0;s>>=1) sum += __shfl_xor(sum, s);
    float inv = (sum > 0.f) ? 1.f/sum : 0.f;
#pragma unroll
    for (int q=0;q<4;q++){ int kk = lane + (q<<6); mw[i][kk] = e[q]*inv; }
  }
  __syncthreads();
  int il = t>>3, d = t&7;
  float s = 0.f;
  for (int kk=0; kk<Nk; kk++) s += mw[il][kk]*sup_s[kk*Dk + d];
  ao[((size_t)b*Nk + i0 + il)*HDk + (h<<3) + d] = s;
}

// gat = tanh(ao + b_gat + support@projW + projB)   (in-place over ao)
__global__ void k_gatout(const float* __restrict__ ao, const float* __restrict__ support,
                         const float* __restrict__ pW, const float* __restrict__ pB,
                         const float* __restrict__ bg, float* __restrict__ gat){
  __shared__ float srow[4][HIDk+1];
  int b = blockIdx.x >> 6; int n0 = (blockIdx.x & 63) << 2;
  int t = threadIdx.x;
  for (int i = t; i < 4*HIDk; i += 256)
    srow[i>>9][i&511] = support[((size_t)b*Nk + n0 + (i>>9))*HIDk + (i&511)];
  __syncthreads();
  int nl = t >> 6, hd = t & 63;
  const float* srw = srow[nl];
  float s = pB[hd] + bg[hd];
  for (int c=0;c<HIDk;c++) s += srw[c]*pW[c*HDk + hd];
  size_t idx = ((size_t)b*Nk + n0 + nl)*HDk + hd;
  gat[idx] = tanhf(s + ao[idx]);
}

// 64x64 tile transpose + bf16 convert: dst[n][k] = (bf16)src[k][n]  (512x512)
__global__ void k_prepT(const float* __restrict__ w_self2, const float* __restrict__ sem_w1,
                        unsigned short* __restrict__ w2T, unsigned short* __restrict__ w1T){
  __shared__ float tile[64][65];
  const float* src = blockIdx.y ? sem_w1 : w_self2;
  unsigned short* dst = blockIdx.y ? w1T : w2T;
  int tk = (blockIdx.x >> 3) << 6;
  int tn = (blockIdx.x & 7) << 6;
  int t = threadIdx.x;
  for (int i = t; i < 64*64; i += 256){
    int r = i >> 6, c = i & 63;
    tile[r][c] = src[(size_t)(tk + r)*HIDk + tn + c];
  }
  __syncthreads();
  for (int i = t; i < 64*64; i += 256){
    int r = i >> 6, c = i & 63;
    dst[(size_t)(tn + r)*HIDk + tk + c] = f2bf(tile[c][r]);
  }
}

// MFMA GEMM: out = A[M][512] @ BT^T, BT = bf16 [512 n][512 k]. NF=8, col-split grid.y=4.
// MODE 0 (S2): out_f[remap(m)*512+col] = acc + bias[col]   (emb channel 0 layout)
// MODE 1 (WSEM): atomicAdd(wsem[m], sum_colslice tanh(acc+bias)*w2)  (wsem pre-zeroed)
template<int MODE>
__global__ __launch_bounds__(256) void k_gemm512(
    const float* __restrict__ A, const unsigned short* __restrict__ BT,
    const float* __restrict__ bias, const float* __restrict__ w2,
    float* __restrict__ outf){
  constexpr int NF = 8;
  constexpr int NPB = NF*16;     // 128
  __shared__ uint4 As4[64*4];
  __shared__ uint4 Bs4[NPB*4];
  int row0 = blockIdx.x << 6;
  int col0 = blockIdx.y * NPB;
  int t = threadIdx.x;
  int w = t >> 6, l = t & 63;
  f32x4 acc[NF];
#pragma unroll
  for (int i=0;i<NF;i++) acc[i] = (f32x4){0.f,0.f,0.f,0.f};

  int lrA = t >> 2;          // 0..63 (row for staging)
  int slot = t & 3;          // k chunk-of-8 for staging
  const float* aptr = A + (size_t)(row0 + lrA)*HIDk + slot*8;
  const unsigned short* bbase = BT + (size_t)(col0 + lrA)*HIDk + slot*8;

  // preload kc = 0
  float4 av0 = *(const float4*)(aptr);
  float4 av1 = *(const float4*)(aptr + 4);
  uint4 bv0  = *(const uint4*)(bbase);
  uint4 bv1  = *(const uint4*)(bbase + (size_t)64*HIDk);

  for (int kc = 0; kc < 512; kc += 32){
    uint4 apk;
    unsigned short* ap = (unsigned short*)&apk;
    ap[0]=f2bf(av0.x); ap[1]=f2bf(av0.y); ap[2]=f2bf(av0.z); ap[3]=f2bf(av0.w);
    ap[4]=f2bf(av1.x); ap[5]=f2bf(av1.y); ap[6]=f2bf(av1.z); ap[7]=f2bf(av1.w);
    __syncthreads();
    As4[(lrA<<2) + (slot ^ ((lrA>>1)&3))] = apk;
    Bs4[(lrA<<2) + (slot ^ ((lrA>>1)&3))] = bv0;
    {
      int ln = 64 + lrA;
      Bs4[(ln<<2) + (slot ^ ((ln>>1)&3))] = bv1;
    }
    __syncthreads();
    if (kc + 32 < 512){
      av0 = *(const float4*)(aptr + kc + 32);
      av1 = *(const float4*)(aptr + kc + 36);
      bv0 = *(const uint4*)(bbase + kc + 32);
      bv1 = *(const uint4*)(bbase + (size_t)64*HIDk + kc + 32);
    }
    int aRow = (w<<4) + (l&15);
    int ks = l>>4;
    short8 af = *(const short8*)&As4[(aRow<<2) + (ks ^ ((aRow>>1)&3))];
#pragma unroll
    for (int nf = 0; nf < NF; nf++){
      int bRow = (nf<<4) + (l&15);
      short8 bfr = *(const short8*)&Bs4[(bRow<<2) + (ks ^ ((bRow>>1)&3))];
      acc[nf] = __builtin_amdgcn_mfma_f32_16x16x32_bf16(af, bfr, acc[nf], 0, 0, 0);
    }
  }
  int colB = l & 15, rg = l >> 4;
  if (MODE == 0){
#pragma unroll
    for (int nf = 0; nf < NF; nf++){
      int col = col0 + (nf<<4) + colB;
      float bb = bias[col];
#pragma unroll
      for (int r = 0; r < 4; r++){
        int m = row0 + (w<<4) + (rg<<2) + r;
        int mo = ((m>>8)<<10) + (m&255);   // emb channel-0 row remap
        outf[(size_t)mo*HIDk + col] = acc[nf][r] + bb;
      }
    }
  } else {
    float s0=0.f, s1=0.f, s2v=0.f, s3=0.f;
#pragma unroll
    for (int nf = 0; nf < NF; nf++){
      int col = col0 + (nf<<4) + colB;
      float bb = bias[col], wv = w2[col];
      s0  += tanhf(acc[nf][0]+bb)*wv;
      s1  += tanhf(acc[nf][1]+bb)*wv;
      s2v += tanhf(acc[nf][2]+bb)*wv;
      s3  += tanhf(acc[nf][3]+bb)*wv;
    }
#pragma unroll
    for (int mk = 1; mk < 16; mk <<= 1){
      s0  += __shfl_xor(s0, mk);  s1 += __shfl_xor(s1, mk);
      s2v += __shfl_xor(s2v, mk); s3 += __shfl_xor(s3, mk);
    }
    if (colB == 0){
      int m = row0 + (w<<4) + (rg<<2);
      atomicAdd(&outf[m+0], s0);
      atomicAdd(&outf[m+1], s1);
      atomicAdd(&outf[m+2], s2v);
      atomicAdd(&outf[m+3], s3);
    }
  }
}

// emb[b,chan,n,:] = gat @ W + bias  (K=64, 8 rows / block)
__global__ void k_mlp(const float* __restrict__ gat, const float* __restrict__ W,
                      const float* __restrict__ bias, float* __restrict__ emb, int chan){
  __shared__ float g[8][HDk];
  int b = blockIdx.x >> 5; int n0 = (blockIdx.x & 31) << 3;
  int t = threadIdx.x;
  for (int i=t;i<8*HDk;i+=256) g[i>>6][i&63] = gat[((size_t)b*Nk + n0 + (i>>6))*HDk + (i&63)];
  __syncthreads();
  for (int pass=0;pass<2;pass++){
    int o = t + (pass<<8);
    float acc[8]={0,0,0,0,0,0,0,0};
    for (int c=0;c<HDk;c++){
      float wv = W[c*HIDk+o];
#pragma unroll
      for (int r=0;r<8;r++) acc[r] += g[r][c]*wv;
    }
    float bs = bias[o];
#pragma unroll
    for (int r=0;r<8;r++) emb[(((size_t)b*4 + chan)*Nk + n0+r)*HIDk + o] = acc[r]+bs;
  }
}

// beta = softmax_c(wsem); fused[b,n,:] = sum_c beta_c * emb[b,c,n,:]
__global__ void k_fused(const float* __restrict__ emb, const float* __restrict__ wsem,
                        float* __restrict__ fused){
  int bn = blockIdx.x; int b = bn>>8, n = bn&255;
  float w0 = wsem[((b<<2)+0)*Nk+n], w1 = wsem[((b<<2)+1)*Nk+n];
  float w2 = wsem[((b<<2)+2)*Nk+n], w3 = wsem[((b<<2)+3)*Nk+n];
  float m = fmaxf(fmaxf(w0,w1),fmaxf(w2,w3));
  float e0=expf(w0-m),e1=expf(w1-m),e2=expf(w2-m),e3=expf(w3-m);
  float inv = 1.f/(e0+e1+e2+e3);
  e0*=inv; e1*=inv; e2*=inv; e3*=inv;
  const float* e = emb + (((size_t)(b<<2))*Nk + n)*HIDk;
  size_t cs = (size_t)Nk*HIDk;
  for (int o = threadIdx.x; o < HIDk; o += 128)
    fused[(size_t)bn*HIDk + o] = e0*e[o] + e1*e[o+cs] + e2*e[o+2*cs] + e3*e[o+3*cs];
}

__global__ void k_cmean(const float* __restrict__ fused, float* __restrict__ cmean){
  int b = blockIdx.x >> 1; int o = ((blockIdx.x & 1) << 8) + threadIdx.x;
  float s=0.f;
  for (int n=0;n<Nk;n++) s += fused[((size_t)b*Nk+n)*HIDk + o];
  cmean[b*HIDk+o] = s*(1.f/Nk);
}

__global__ void k_norm(const float* __restrict__ fused, const float* __restrict__ cmean,
                       float* __restrict__ xc){
  __shared__ float red[4];
  int bn = blockIdx.x; int b = bn>>8;
  int t = threadIdx.x;
  float v0 = fused[(size_t)bn*HIDk + t]       - cmean[b*HIDk + t];
  float v1 = fused[(size_t)bn*HIDk + t+256]   - cmean[b*HIDk + t+256];
  float ss = v0*v0 + v1*v1;
#pragma unroll
  for (int s=32;s>0;s>>=1) ss += __shfl_xor(ss, s);
  if ((t&63)==0) red[t>>6] = ss;
  __syncthreads();
  float tot = red[0]+red[1]+red[2]+red[3];
  float inv = 1.0f/sqrtf(1e-6f + tot);
  xc[(size_t)bn*HIDk + t]     = v0*inv;
  xc[(size_t)bn*HIDk + t+256] = v1*inv;
}

// per (n,q): part[b][(n*4+q)][g] = sum_{c in q-slice} xc[b,n,c]*gen_w[n*512+c, g]
// xc slice staged in LDS (16 KB), broadcast ds_read_b128 per (b,c-chunk);
// gen_w rows prefetched 4-deep into registers (4 independent 256B loads in flight).
__global__ __launch_bounds__(256) void k_gen(const float* __restrict__ xc, const float* __restrict__ genw,
                                             float* __restrict__ part){
  __shared__ float xs[Bk][128];    // 16 KB
  int n = blockIdx.x, q = blockIdx.y;
  int t = threadIdx.x;
  int c0 = q << 7;
  for (int i = t; i < Bk*128/4; i += 256){
    int b = i >> 5;                 // 32 float4 per b-row
    int c = (i & 31) << 2;
    *(float4*)&xs[b][c] = *(const float4*)(xc + ((size_t)b*Nk + n)*HIDk + c0 + c);
  }
  __syncthreads();
  float acc[32];
#pragma unroll
  for (int b=0;b<32;b++) acc[b]=0.f;
  const float* wp = genw + ((size_t)n*HIDk + c0)*Nk + t;
  float w0 = wp[0];
  float w1 = wp[(size_t)1*Nk];
  float w2 = wp[(size_t)2*Nk];
  float w3 = wp[(size_t)3*Nk];
  for (int c = 0; c < 128; c += 4){
    float x0=w0, x1=w1, x2=w2, x3=w3;
    if (c + 4 < 128){
      w0 = wp[(size_t)(c+4)*Nk];
      w1 = wp[(size_t)(c+5)*Nk];
      w2 = wp[(size_t)(c+6)*Nk];
      w3 = wp[(size_t)(c+7)*Nk];
    }
#pragma unroll
    for (int b = 0; b < 32; b++){
      float4 xv = *(const float4*)&xs[b][c];
      acc[b] = fmaf(xv.x, x0, fmaf(xv.y, x1, fmaf(xv.z, x2, fmaf(xv.w, x3, acc[b]))));
    }
  }
#pragma unroll
  for (int b=0;b<32;b++) part[((size_t)b*(Nk*GSLICE) + (n<<2) + q)*Nk + t] = acc[b];
}

__global__ void k_final(const float* __restrict__ part, const float* __restrict__ genb,
                        float* __restrict__ out){
  int b = blockIdx.x, g = threadIdx.x;
  float s0=0.f, s1=0.f, s2=0.f, s3=0.f;
  const float* p = part + (size_t)b*(Nk*GSLICE)*Nk + g;
  for (int s = 0; s < Nk*GSLICE; s += 4){
    s0 += p[(size_t)(s+0)*Nk];
    s1 += p[(size_t)(s+1)*Nk];
    s2 += p[(size_t)(s+2)*Nk];
    s3 += p[(size_t)(s+3)*Nk];
  }
  float s = genb[g] + s0+s1+s2+s3;
  out[b*Nk + g] = 1.f/(1.f + expf(-s));
}

extern "C" void kernel_launch(void* const* d_in, const int* in_sizes, int n_in,
                              void* d_out, int out_size, void* d_ws, size_t ws_size,
                              hipStream_t stream){
  const float* inp    = (const float*)d_in[0];
  const float* W_gat  = (const float*)d_in[1];
  const float* Wu     = (const float*)d_in[2];
  const float* Wv     = (const float*)d_in[3];
  const float* b_gat  = (const float*)d_in[4];
  const float* projW  = (const float*)d_in[5];
  const float* projB  = (const float*)d_in[6];
  const float* w_self1= (const float*)d_in[7];
  const float* b_self1= (const float*)d_in[8];
  const float* w_mlp  = (const float*)d_in[9];
  const float* b_mlp  = (const float*)d_in[10];
  const float* w_self2= (const float*)d_in[11];
  const float* b_self2= (const float*)d_in[12];
  const float* sem_w1 = (const float*)d_in[13];
  const float* sem_b1 = (const float*)d_in[14];
  const float* sem_w2 = (const float*)d_in[15];
  const float* gen_w  = (const float*)d_in[16];
  const float* gen_b  = (const float*)d_in[17];
  float* out = (float*)d_out;
  (void)in_sizes; (void)n_in; (void)out_size; (void)ws_size;

  float* w = (float*)d_ws;
  size_t off = 0;
  auto A = [&](size_t n){ float* p = w + off; off += (n + 63) & ~(size_t)63; return p; };
  float* support = A((size_t)Bk*Nk*HIDk);
  float* emb     = A((size_t)Bk*4*Nk*HIDk);
  float* sup0 = A((size_t)Bk*Hk*Nk*Dk); float* sup1 = A((size_t)Bk*Hk*Nk*Dk);
  float* fu0  = A(Bk*Hk*Nk); float* fu1 = A(Bk*Hk*Nk);
  float* fv0  = A(Bk*Hk*Nk); float* fv1 = A(Bk*Hk*Nk);
  float* zs0  = A(Bk*Hk*Nk); float* zs1 = A(Bk*Hk*Nk);
  float* ao0  = A((size_t)Bk*Nk*HDk); float* ao1 = A((size_t)Bk*Nk*HDk);
  float* wsem = A(Bk*4*Nk);
  float* fused= A((size_t)Bk*Nk*HIDk);
  float* cmean= A(Bk*HIDk);
  float* part = A((size_t)Bk*Nk*GSLICE*Nk);
  float* tbuf = A(2*HIDk*HIDk/2);       // 2 bf16 matrices of 512x512 = 1MB
  unsigned short* w2T = (unsigned short*)tbuf;
  unsigned short* w1T = w2T + HIDk*HIDk;
  int* ib  = (int*)(w + off);
  int* zc0 = ib;              int* zc1 = zc0 + Bk;
  int* zi0 = zc1 + Bk;        int* zi1 = zi0 + Bk*Nk;
  int* cc0 = zi1 + Bk*Nk;     int* cc1 = cc0 + Bk*Nk;
  int* ri0 = cc1 + Bk*Nk;     int* ri1 = ri0 + (size_t)Bk*Nk*CAPk;

  hipMemsetAsync(zc0, 0, 2*Bk*sizeof(int), stream);
  hipMemsetAsync(wsem, 0, (size_t)Bk*4*Nk*sizeof(float), stream);
  k_prepT<<<dim3(64,2), 256, 0, stream>>>(w_self2, sem_w1, w2T, w1T);
  k_support<<<Bk*Nk, 256, 0, stream>>>(inp, w_self1, b_self1, support);
  k_sup<<<Bk*(Nk/4), 256, 0, stream>>>(support, W_gat, sup0);
  k_sup<<<Bk*(Nk/4), 256, 0, stream>>>(support, W_gat + 2*HIDk*HDk, sup1);
  k_fuv<<<Bk*Hk*Nk/256, 256, 0, stream>>>(sup0, Wu, Wv, fu0, fv0);
  k_fuv<<<Bk*Hk*Nk/256, 256, 0, stream>>>(sup1, Wu + 2*Hk*Dk, Wv + 2*Hk*Dk, fu1, fv1);
  k_rowzero<<<Bk*Nk, 256, 0, stream>>>(inp, 0,    zc0, zi0);
  k_rowzero<<<Bk*Nk, 256, 0, stream>>>(inp, 2*Nk, zc1, zi1);
  k_csc<<<Bk*Nk, 256, 0, stream>>>(inp, 0,    cc0, ri0);
  k_csc<<<Bk*Nk, 256, 0, stream>>>(inp, 2*Nk, cc1, ri1);
  k_zsum<<<Bk*Hk*Nk/256, 256, 0, stream>>>(fu0, fv0, zc0, zi0, zs0);
  k_zsum<<<Bk*Hk*Nk/256, 256, 0, stream>>>(fu1, fv1, zc1, zi1, zs1);
  k_attn<<<Bk*Hk*(Nk/32), 256, 0, stream>>>(sup0, fu0, fv0, zs0, zc0, cc0, ri0, ao0);
  k_attn<<<Bk*Hk*(Nk/32), 256, 0, stream>>>(sup1, fu1, fv1, zs1, zc1, cc1, ri1, ao1);
  k_gatout<<<Bk*(Nk/4), 256, 0, stream>>>(ao0, support, projW,                projB,         b_gat,         ao0);
  k_gatout<<<Bk*(Nk/4), 256, 0, stream>>>(ao1, support, projW + 2*HIDk*HDk,   projB + 2*HDk, b_gat + 2*HDk, ao1);
  k_gemm512<0><<<dim3(128,4), 256, 0, stream>>>(support, w2T, b_self2, nullptr, emb);
  k_mlp<<<Bk*(Nk/8), 256, 0, stream>>>(ao0, w_mlp,               b_mlp,          emb, 1);
  k_mlp<<<Bk*(Nk/8), 256, 0, stream>>>(ao1, w_mlp + HDk*HIDk,    b_mlp + HIDk,   emb, 2);
  k_mlp<<<Bk*(Nk/8), 256, 0, stream>>>(ao1, w_mlp + 2*HDk*HIDk,  b_mlp + 2*HIDk, emb, 3);
  k_gemm512<1><<<dim3(512,4), 256, 0, stream>>>(emb, w1T, sem_b1, sem_w2, wsem);
  k_fused<<<Bk*Nk, 128, 0, stream>>>(emb, wsem, fused);
  k_cmean<<<Bk*2, 256, 0, stream>>>(fused, cmean);
  k_norm<<<Bk*Nk, 256, 0, stream>>>(fused, cmean, fused);
  k_gen<<<dim3(Nk, GSLICE), 256, 0, stream>>>(fused, gen_w, part);
  k_final<<<Bk, 256, 0, stream>>>(part, gen_b, out);
}